// Round 4
// baseline (447.044 us; speedup 1.0000x reference)
//
#include <hip/hip_runtime.h>

// 3x3 conv, stride 1, pad 1, NCHW, C=1. eff_w[i][j] = weight[i][j]*kx[i]*kx[j],
// kx = [den, 1, den]. x: (16,1,2048,2048) fp32 -> out same shape fp32.
//
// v5 = v4 + non-temporal stores (SINGLE isolated change).
// Rationale: conv portion stuck at ~104us over v1/v4 = 5.8 TB/s IF reads miss
// L3 (600 MB total). x (268MB) barely exceeds L3 (256MB); the write stream
// allocating in L2/L3 thrashes x's residency. v2 measured FETCH=136MB *with*
// NT stores -> half of x served by L3 when writes bypass. v3's 12us regression
// bundled NT+swizzle; betting it was the swizzle. If this regresses, NT was
// the culprit -> revert to v4 and declare roofline.

#define IMG_W 2048
#define IMG_H 2048
#define BATCH 16
#define RPT 8                       // rows per thread
#define WCHUNKS (IMG_W / 4)         // 512 float4 chunks per row
#define ROWGRPS (IMG_H / RPT)       // 256 row-groups per image
#define NTHREADS (WCHUNKS * ROWGRPS * BATCH)  // 2,097,152
#define NBLOCKS (NTHREADS / 256)    // 8192

typedef float f4 __attribute__((ext_vector_type(4)));

__global__ __launch_bounds__(256) void conv3x3_kernel(
    const float* __restrict__ x,
    const float* __restrict__ weight,
    const float* __restrict__ den,
    float* __restrict__ out)
{
    const int tid    = (int)blockIdx.x * 256 + (int)threadIdx.x;
    const int lane   = (int)threadIdx.x & 63;
    const int wchunk = tid & (WCHUNKS - 1);        // 9 bits
    const int rowgrp = (tid >> 9) & (ROWGRPS - 1); // 8 bits
    const int b      = tid >> 17;

    const float* xb = x   + (size_t)b * IMG_H * IMG_W;
    float*       ob = out + (size_t)b * IMG_H * IMG_W;
    const int w0 = wchunk * 4;
    const int h0 = rowgrp * RPT;
    // wchunk==0 implies lane==0; wchunk==511 implies lane==63 (512 % 64 == 0),
    // so interior lanes ALWAYS have a valid in-wave neighbor for the halo.
    const bool has_l = (w0 > 0);
    const bool has_r = (w0 + 4 < IMG_W);

    // ---- phase 1: issue ALL row loads (independent; ~12 VMEM ops in flight)
    f4    c[RPT + 2];
    float le[RPT + 2], re[RPT + 2];
#pragma unroll
    for (int i = 0; i < RPT + 2; ++i) {
        const int h = h0 - 1 + i;
        le[i] = 0.0f; re[i] = 0.0f;
        if (h < 0 || h >= IMG_H) {   // wave-uniform (rowgrp uniform in wave)
            c[i] = (f4)0.0f;
            continue;
        }
        const float* r = xb + (size_t)h * IMG_W + w0;
        c[i] = *(const f4*)r;
        if (lane == 0  && has_l) le[i] = r[-1];
        if (lane == 63 && has_r) re[i] = r[4];
    }

    // effective 3x3 weights (scalar path; computed while loads are in flight)
    const float d = den[0];
    const float k[3] = {d, 1.0f, d};
    float wgt[3][3];
#pragma unroll
    for (int i = 0; i < 3; ++i)
#pragma unroll
        for (int j = 0; j < 3; ++j)
            wgt[i][j] = weight[i * 3 + j] * k[i] * k[j];

    // ---- phase 2: derive horizontal halo in-register via wave shuffles.
    float v0[RPT + 2], v5[RPT + 2];
#pragma unroll
    for (int i = 0; i < RPT + 2; ++i) {
        const float ls = __shfl_up(c[i].w, 1);    // lane l <- lane l-1 col w0-1
        const float rs = __shfl_down(c[i].x, 1);  // lane l <- lane l+1 col w0+4
        v0[i] = (lane == 0)  ? le[i] : ls;
        v5[i] = (lane == 63) ? re[i] : rs;
    }

    // row element k (k=0..5 spanning cols w0-1 .. w0+4), constant k only:
#define EL(i, k) ((k) == 0 ? v0[i] : ((k) == 5 ? v5[i] : c[i][(k) - 1]))

    // ---- phase 3: compute + NON-TEMPORAL store. out is never re-read;
    // keeping it out of L2/L3 preserves x's residency (the isolated change).
#pragma unroll
    for (int rr = 0; rr < RPT; ++rr) {
        f4 o;
#pragma unroll
        for (int j = 0; j < 4; ++j) {
            o[j] = wgt[0][0]*EL(rr,   j) + wgt[0][1]*EL(rr,   j+1) + wgt[0][2]*EL(rr,   j+2)
                 + wgt[1][0]*EL(rr+1, j) + wgt[1][1]*EL(rr+1, j+1) + wgt[1][2]*EL(rr+1, j+2)
                 + wgt[2][0]*EL(rr+2, j) + wgt[2][1]*EL(rr+2, j+1) + wgt[2][2]*EL(rr+2, j+2);
        }
        __builtin_nontemporal_store(
            o, (f4*)(ob + (size_t)(h0 + rr) * IMG_W + w0));
    }
#undef EL
}

extern "C" void kernel_launch(void* const* d_in, const int* in_sizes, int n_in,
                              void* d_out, int out_size, void* d_ws, size_t ws_size,
                              hipStream_t stream) {
    const float* x      = (const float*)d_in[0];
    const float* weight = (const float*)d_in[1];
    const float* den    = (const float*)d_in[2];
    float*       out    = (float*)d_out;

    conv3x3_kernel<<<NBLOCKS, 256, 0, stream>>>(x, weight, den, out);
}

// Round 6
// 440.438 us; speedup vs baseline: 1.0150x; 1.0150x over previous
//
#include <hip/hip_runtime.h>

// 3x3 conv, stride 1, pad 1, NCHW, C=1. eff_w[i][j] = weight[i][j]*kx[i]*kx[j],
// kx = [den, 1, den]. x: (16,1,2048,2048) fp32 -> out same shape fp32.
//
// v6 (resubmit; round-5 bench was an infra failure, no data) = v4 with
// RPT 8 -> 16 (SINGLE mechanism change: vertical halo read amplification
// 10/8=1.25x -> 18/16=1.125x, -33 MB issued halo loads).
// Ledger: NT stores +12us (v5), XCD swizzle ~0 (v3 vs v5), shuffle-halo ~0
// (v4 vs v1), explicit preload required (v2: VGPR=36, latency-bound, 191us).
// VGPR control for RPT=16: (a) ONE packed edge reg/row (lane0=left halo,
// lane63=right halo -- disjoint lanes share the register); (b) shuffle-derived
// halo computed just-in-time in the compute loop (live window ~3), not as a
// whole-array phase. Target VGPR <= 128 (occupancy cliff).

#define IMG_W 2048
#define IMG_H 2048
#define BATCH 16
#define RPT 16                      // rows per thread
#define WCHUNKS (IMG_W / 4)         // 512 float4 chunks per row
#define ROWGRPS (IMG_H / RPT)       // 128 row-groups per image
#define NTHREADS (WCHUNKS * ROWGRPS * BATCH)  // 1,048,576
#define NBLOCKS (NTHREADS / 256)    // 4096

typedef float f4 __attribute__((ext_vector_type(4)));

__global__ __launch_bounds__(256) void conv3x3_kernel(
    const float* __restrict__ x,
    const float* __restrict__ weight,
    const float* __restrict__ den,
    float* __restrict__ out)
{
    const int tid    = (int)blockIdx.x * 256 + (int)threadIdx.x;
    const int lane   = (int)threadIdx.x & 63;
    const int wchunk = tid & (WCHUNKS - 1);        // 9 bits
    const int rowgrp = (tid >> 9) & (ROWGRPS - 1); // 7 bits
    const int b      = tid >> 16;                  // 512*128 = 2^16 per image

    const float* xb = x   + (size_t)b * IMG_H * IMG_W;
    float*       ob = out + (size_t)b * IMG_H * IMG_W;
    const int w0 = wchunk * 4;
    const int h0 = rowgrp * RPT;
    // wchunk==0 implies lane==0; wchunk==511 implies lane==63 (512 % 64 == 0),
    // so interior lanes ALWAYS have a valid in-wave neighbor for the halo.
    const bool is_l  = (lane == 0);
    const bool is_r  = (lane == 63);
    const bool edge_ld = (is_l && w0 > 0) || (is_r && w0 + 4 < IMG_W);
    const int  eoff  = is_l ? -1 : 4;   // lane0 reads col w0-1, lane63 col w0+4

    // ---- phase 1: issue ALL row loads (independent; 18 dwordx4 + 18
    // exec-masked edge scalars in flight per wave -> latency fully covered)
    f4    c[RPT + 2];
    float edge[RPT + 2];   // lane0: left halo val; lane63: right halo val
#pragma unroll
    for (int i = 0; i < RPT + 2; ++i) {
        const int h = h0 - 1 + i;
        edge[i] = 0.0f;
        if (h < 0 || h >= IMG_H) {   // wave-uniform (rowgrp uniform in wave)
            c[i] = (f4)0.0f;
            continue;
        }
        const float* r = xb + (size_t)h * IMG_W + w0;
        c[i] = *(const f4*)r;
        if (edge_ld) edge[i] = r[eoff];  // 2 active lanes; L1/L2 hit
    }

    // effective 3x3 weights (scalar path; computed while loads are in flight)
    const float d = den[0];
    const float k[3] = {d, 1.0f, d};
    float wgt[3][3];
#pragma unroll
    for (int i = 0; i < 3; ++i)
#pragma unroll
        for (int j = 0; j < 3; ++j)
            wgt[i][j] = weight[i * 3 + j] * k[i] * k[j];

    // ---- phase 2+3 fused: derive horizontal halo just-in-time (live window
    // of ~3 rows keeps VGPR under the 128 cliff), compute, plain f4 store.
    float v0[RPT + 2], v5[RPT + 2];
    auto halo = [&](int i) {
        const float ls = __shfl_up(c[i].w, 1);    // lane l <- l-1 col w0-1
        const float rs = __shfl_down(c[i].x, 1);  // lane l <- l+1 col w0+4
        v0[i] = is_l ? edge[i] : ls;
        v5[i] = is_r ? edge[i] : rs;
    };

    // row element k (k=0..5 spanning cols w0-1 .. w0+4), constant k only:
#define EL(i, k) ((k) == 0 ? v0[i] : ((k) == 5 ? v5[i] : c[i][(k) - 1]))

    halo(0);
    halo(1);
#pragma unroll
    for (int rr = 0; rr < RPT; ++rr) {
        halo(rr + 2);
        f4 o;
#pragma unroll
        for (int j = 0; j < 4; ++j) {
            o[j] = wgt[0][0]*EL(rr,   j) + wgt[0][1]*EL(rr,   j+1) + wgt[0][2]*EL(rr,   j+2)
                 + wgt[1][0]*EL(rr+1, j) + wgt[1][1]*EL(rr+1, j+1) + wgt[1][2]*EL(rr+1, j+2)
                 + wgt[2][0]*EL(rr+2, j) + wgt[2][1]*EL(rr+2, j+1) + wgt[2][2]*EL(rr+2, j+2);
        }
        *(f4*)(ob + (size_t)(h0 + rr) * IMG_W + w0) = o;
    }
#undef EL
}

extern "C" void kernel_launch(void* const* d_in, const int* in_sizes, int n_in,
                              void* d_out, int out_size, void* d_ws, size_t ws_size,
                              hipStream_t stream) {
    const float* x      = (const float*)d_in[0];
    const float* weight = (const float*)d_in[1];
    const float* den    = (const float*)d_in[2];
    float*       out    = (float*)d_out;

    conv3x3_kernel<<<NBLOCKS, 256, 0, stream>>>(x, weight, den, out);
}

// Round 7
// 435.832 us; speedup vs baseline: 1.0257x; 1.0106x over previous
//
#include <hip/hip_runtime.h>

// 3x3 conv, stride 1, pad 1, NCHW, C=1. eff_w[i][j] = weight[i][j]*kx[i]*kx[j],
// kx = [den, 1, den]. x: (16,1,2048,2048) fp32 -> out same shape fp32.
//
// v7 = exact revert to v4 (best measured: 435.1us; v1 tied at 434.6).
// Full isolated-change ledger across the session:
//   shuffle-halo (v4 vs v1): ~0    | XCD swizzle (v3 vs v5): ~0
//   NT stores    (v5 vs v4): +12us | RPT=16      (v6 vs v4): +5us
//   RPT=32 w/o preload (v2): +52us (VGPR=36, compiler hoists nothing,
//                                   latency-bound at 2.1 TB/s)
// Conv portion ~104us = ~604 MB issued @ 5.8 TB/s ~= 92% of the 6.29 TB/s
// pure-stream ceiling; mixed read+write lands below pure-stream. Two
// structurally different kernels (v1/v4) tie within 0.5us -> BW-bound.
// This is the mixed-stream HBM roofline for this op.

#define IMG_W 2048
#define IMG_H 2048
#define BATCH 16
#define RPT 8                       // rows per thread
#define WCHUNKS (IMG_W / 4)         // 512 float4 chunks per row
#define ROWGRPS (IMG_H / RPT)       // 256 row-groups per image
#define NTHREADS (WCHUNKS * ROWGRPS * BATCH)  // 2,097,152
#define NBLOCKS (NTHREADS / 256)    // 8192

typedef float f4 __attribute__((ext_vector_type(4)));

__global__ __launch_bounds__(256) void conv3x3_kernel(
    const float* __restrict__ x,
    const float* __restrict__ weight,
    const float* __restrict__ den,
    float* __restrict__ out)
{
    const int tid    = (int)blockIdx.x * 256 + (int)threadIdx.x;
    const int lane   = (int)threadIdx.x & 63;
    const int wchunk = tid & (WCHUNKS - 1);        // 9 bits
    const int rowgrp = (tid >> 9) & (ROWGRPS - 1); // 8 bits
    const int b      = tid >> 17;

    const float* xb = x   + (size_t)b * IMG_H * IMG_W;
    float*       ob = out + (size_t)b * IMG_H * IMG_W;
    const int w0 = wchunk * 4;
    const int h0 = rowgrp * RPT;
    // wchunk==0 implies lane==0; wchunk==511 implies lane==63 (512 % 64 == 0),
    // so interior lanes ALWAYS have a valid in-wave neighbor for the halo.
    const bool has_l = (w0 > 0);
    const bool has_r = (w0 + 4 < IMG_W);

    // ---- phase 1: issue ALL row loads (independent; ~12 VMEM ops in flight
    // per wave). Explicit preload is REQUIRED: under partial unroll the
    // compiler hoists nothing (v2: VGPR=36 -> latency-bound).
    f4    c[RPT + 2];
    float le[RPT + 2], re[RPT + 2];
#pragma unroll
    for (int i = 0; i < RPT + 2; ++i) {
        const int h = h0 - 1 + i;
        le[i] = 0.0f; re[i] = 0.0f;
        if (h < 0 || h >= IMG_H) {   // wave-uniform (rowgrp uniform in wave)
            c[i] = (f4)0.0f;
            continue;
        }
        const float* r = xb + (size_t)h * IMG_W + w0;
        c[i] = *(const f4*)r;
        if (lane == 0  && has_l) le[i] = r[-1];
        if (lane == 63 && has_r) re[i] = r[4];
    }

    // effective 3x3 weights (scalar path; computed while loads are in flight)
    const float d = den[0];
    const float k[3] = {d, 1.0f, d};
    float wgt[3][3];
#pragma unroll
    for (int i = 0; i < 3; ++i)
#pragma unroll
        for (int j = 0; j < 3; ++j)
            wgt[i][j] = weight[i * 3 + j] * k[i] * k[j];

    // ---- phase 2: derive horizontal halo in-register via wave shuffles.
    float v0[RPT + 2], v5[RPT + 2];
#pragma unroll
    for (int i = 0; i < RPT + 2; ++i) {
        const float ls = __shfl_up(c[i].w, 1);    // lane l <- lane l-1 col w0-1
        const float rs = __shfl_down(c[i].x, 1);  // lane l <- lane l+1 col w0+4
        v0[i] = (lane == 0)  ? le[i] : ls;
        v5[i] = (lane == 63) ? re[i] : rs;
    }

    // row element k (k=0..5 spanning cols w0-1 .. w0+4), constant k only:
#define EL(i, k) ((k) == 0 ? v0[i] : ((k) == 5 ? v5[i] : c[i][(k) - 1]))

    // ---- phase 3: compute + plain f4 store (NT stores measured +12us)
#pragma unroll
    for (int rr = 0; rr < RPT; ++rr) {
        f4 o;
#pragma unroll
        for (int j = 0; j < 4; ++j) {
            o[j] = wgt[0][0]*EL(rr,   j) + wgt[0][1]*EL(rr,   j+1) + wgt[0][2]*EL(rr,   j+2)
                 + wgt[1][0]*EL(rr+1, j) + wgt[1][1]*EL(rr+1, j+1) + wgt[1][2]*EL(rr+1, j+2)
                 + wgt[2][0]*EL(rr+2, j) + wgt[2][1]*EL(rr+2, j+1) + wgt[2][2]*EL(rr+2, j+2);
        }
        *(f4*)(ob + (size_t)(h0 + rr) * IMG_W + w0) = o;
    }
#undef EL
}

extern "C" void kernel_launch(void* const* d_in, const int* in_sizes, int n_in,
                              void* d_out, int out_size, void* d_ws, size_t ws_size,
                              hipStream_t stream) {
    const float* x      = (const float*)d_in[0];
    const float* weight = (const float*)d_in[1];
    const float* den    = (const float*)d_in[2];
    float*       out    = (float*)d_out;

    conv3x3_kernel<<<NBLOCKS, 256, 0, stream>>>(x, weight, den, out);
}